// Round 6
// baseline (344.954 us; speedup 1.0000x reference)
//
#include <hip/hip_runtime.h>

// ---------------------------------------------------------------- constants
#define TTOK 32768
#define DM   256
#define NF   1024
#define KMAX 32

typedef __attribute__((ext_vector_type(8))) unsigned short ushort8;
typedef __attribute__((ext_vector_type(8))) __bf16 bf16x8;
typedef __attribute__((ext_vector_type(4))) float floatx4;
typedef __attribute__((ext_vector_type(2))) float floatx2;

// packed f32 math (lowers to v_pk_fma_f32 / v_pk_max_f32 / v_pk_min_f32)
#define PKFMA(a,b,c) __builtin_elementwise_fma(a,b,c)
#define PKMAX(a,b)   __builtin_elementwise_max(a,b)
#define PKMIN(a,b)   __builtin_elementwise_min(a,b)

// workspace offsets (all 256B aligned)
constexpr size_t O_SLOT = 0;                                   // 1 uint (max|Wt|)
constexpr size_t O_S    = 256;                                 // 1024 f32 sigmoid(alpha)
constexpr size_t O_WCT  = O_S    + 4096;                       // Wc^T  [1024][256] bf16
constexpr size_t O_WGT  = O_WCT  + (size_t)NF*DM*2;            // Wg^T  [1024][256] bf16
constexpr size_t O_WDT  = O_WGT  + (size_t)NF*DM*2;            // Wd^T  [256][1024] bf16
constexpr size_t O_WTT  = O_WDT  + (size_t)DM*NF*2;            // Wt^T  [256][1024] f32
constexpr size_t O_XBF  = O_WTT  + (size_t)DM*NF*4;            // x bf16 [T][256]
constexpr size_t O_CNT  = O_XBF  + (size_t)TTOK*DM*2;          // counts [T]
constexpr size_t O_CIDX = O_CNT  + (size_t)TTOK*4;             // cand d (raw) [T][KMAX]
constexpr size_t O_CVAL = O_CIDX + (size_t)TTOK*KMAX*4;        // cand val [T][KMAX]
constexpr size_t O_FUSD = O_CVAL + (size_t)TTOK*KMAX*4;        // fused bf16 [T][1024]

__device__ __forceinline__ float bf2f(unsigned short u) {
    union { unsigned int i; float f; } c; c.i = ((unsigned int)u) << 16; return c.f;
}
__device__ __forceinline__ unsigned short f2bf(float v) {
    union { float f; unsigned int i; } c; c.f = v;
    unsigned int b = c.i;
    return (unsigned short)((b + 0x7FFFu + ((b >> 16) & 1u)) >> 16);
}
__device__ __forceinline__ float sigm(float z) { return 1.0f / (1.0f + __expf(-z)); }
// tanh-gelu: max |diff| vs exact erf-gelu ~3e-3, far under 0.266 tolerance
__device__ __forceinline__ float gelu_f(float x) {
    return x * sigm(1.59576912f * (x + 0.044715f * x * x * x));
}
// async global->LDS, 16B per lane; lds dest = wave-uniform base + lane*16 [m97/m104]
__device__ __forceinline__ void g2lds16(const unsigned short* g, unsigned short* l) {
    __builtin_amdgcn_global_load_lds((const __attribute__((address_space(1))) unsigned int*)g,
                                     (__attribute__((address_space(3))) unsigned int*)l, 16, 0, 0);
}

// ------------------------------------------------- kernel 1: pack weights (r0 verbatim)
__global__ void pack_kernel(const float* __restrict__ Wt, const float* __restrict__ alpha,
                            const float* __restrict__ Wc, const float* __restrict__ Wg,
                            const float* __restrict__ Wd,
                            unsigned short* __restrict__ Wct, unsigned short* __restrict__ Wgt,
                            unsigned short* __restrict__ WdT, float* __restrict__ WtT,
                            float* __restrict__ s, unsigned int* __restrict__ slot) {
    int e = blockIdx.x * 256 + threadIdx.x;
    if (e == 0) *slot = 0u;
    { int f = e >> 8, k = e & 255;           // Wc/Wg are [256][1024]
      Wct[e] = f2bf(Wc[k * NF + f]);
      Wgt[e] = f2bf(Wg[k * NF + f]); }
    { int n = e >> 10, k = e & 1023;         // Wd is [1024][256]
      WdT[e] = f2bf(Wd[k * DM + n]); }
    { int d = e >> 10, f = e & 1023;         // Wt is [1024][256]
      WtT[e] = Wt[f * DM + d]; }
    if (e < NF) s[e] = sigm(alpha[e]);
}

// ------------------------------------------------- kernel 2: max|Wt| reduce (r0 verbatim)
__global__ void minmax_kernel(const float* __restrict__ Wt, unsigned int* __restrict__ slot) {
    int g = blockIdx.x * 256 + threadIdx.x;
    float lm = 0.0f;
    for (int i = g; i < NF * DM; i += 128 * 256) lm = fmaxf(lm, fabsf(Wt[i]));
    #pragma unroll
    for (int o = 32; o > 0; o >>= 1) lm = fmaxf(lm, __shfl_xor(lm, o));
    if ((threadIdx.x & 63) == 0) atomicMax(slot, __float_as_uint(lm)); // |w|>=0: uint order ok
}

// ------------------------------------------------- kernel 3: candidates + x->bf16 (r0 verbatim)
__global__ void cand_kernel(const float* __restrict__ x, const unsigned int* __restrict__ slot,
                            unsigned short* __restrict__ xbf, int* __restrict__ counts,
                            int* __restrict__ cidx, float* __restrict__ cval) {
    int i = blockIdx.x, t = threadIdx.x;
    float v = x[i * DM + t];
    xbf[i * DM + t] = f2bf(v);
    float m = v;
    #pragma unroll
    for (int o = 32; o > 0; o >>= 1) m = fmaxf(m, __shfl_xor(m, o));
    __shared__ float wm[4];
    __shared__ int cnt;
    __shared__ int sidx[KMAX];
    __shared__ float sval[KMAX];
    if ((t & 63) == 0) wm[t >> 6] = m;
    if (t == 0) cnt = 0;
    __syncthreads();
    float xmax = fmaxf(fmaxf(wm[0], wm[1]), fmaxf(wm[2], wm[3]));
    float delta = 2.0f * __uint_as_float(*slot);   // >= Wmax - Wmin : exact exclusion bound
    float thr = xmax - delta;
    if (v >= thr) {
        int p = atomicAdd(&cnt, 1);
        if (p < KMAX) { sidx[p] = t; sval[p] = v; }   // raw d index
    }
    __syncthreads();
    int c = cnt;
    if (t == 0) counts[i] = c;
    if (t < (c < KMAX ? c : KMAX)) {
        cidx[i * KMAX + t] = sidx[t];
        cval[i * KMAX + t] = sval[t];
    }
}

// ------------------------------------------------- kernel 4: fused GEMM1
// (x@Wc, x@Wg) MFMA + tropical max-plus + convex/concave + gate blend.
// 128x128 tile, BK=32, 512 thr (8 waves 2Mx4F, wave 64x32 dual-output).
// Ledger:
//  r7(128x64+reg-diet): spills+L2 thrash. REVERTED.
//  r8(DB 1-barrier loop): no win. DROPPED. r8(pre-loop prestage): spills. DROPPED.
//  r9(packed epilogue): gemm1 190->178. KEPT. r10(floatx2-direct par): FAIL. REVERTED.
//  r5(r0 structure + r3 pk epilogue): VERIFIED 150us, WRITE=65536 exactly.
//  r6 (this): LATENCY-bound diagnosis -- VALUBusy is per-CU; issue floor of the
//    epilogue is ~30-40us vs ~130us measured => the gather's dynamic loop
//    serializes (sOV ds ~120cy -> addr -> L2 ~300cy -> PKMAX) and 4 waves/SIMD
//    can't hide it. Breadth was blocked by the 128-unified-reg cliff (64 arch
//    + 64 AGPR acc). Fix: PHASE SPLIT -- consume acc right after the K-loop
//    (g=sigm, cla=gelu, pack (g,(1-g)*cla) as 2xbf16/u32 -> 32 regs, frees 64
//    AGPR), then gather with 2x manual unroll (sOV PADV padding makes even
//    trip safe). bc/bg read direct from global in phase 1 (L2-hot).
//    Falsifiable: WRITE_SIZE must stay 65536KB and Occupancy ~42%.
#define LDSS 32   // ushorts per LDS row, no pad (wave-uniform-base DMA, m104)
#define KPAD 33
#define OSTR 136  // obuf row stride in ushorts (272B, 16q+4r+col bank spread)
__global__ __launch_bounds__(512, 4) void gemm1_kernel(
    const unsigned short* __restrict__ A,   // xbf [T][256]
    const unsigned short* __restrict__ Bct, // [1024][256]
    const unsigned short* __restrict__ Bgt, // [1024][256]
    const float* __restrict__ bc, const float* __restrict__ bg,
    const int* __restrict__ counts, const int* __restrict__ cidx,
    const float* __restrict__ cval, const float* __restrict__ x,
    const float* __restrict__ WtT, const float* __restrict__ bt,
    const float* __restrict__ slx, const float* __restrict__ ofx,
    const float* __restrict__ slc, const float* __restrict__ ofc,
    const float* __restrict__ s, unsigned short* __restrict__ fused) {
    __shared__ __align__(16) char smem[76800];
    unsigned short* As  = (unsigned short*)smem;            // [0, 8K)     K-loop
    unsigned short* Bcs = As + 4096;                        // [8K, 16K)   K-loop
    unsigned short* Bgs = As + 8192;                        // [16K, 24K)  K-loop
    float* par = (float*)smem;                              // [0, 18K)    epilogue (overlay)
    int* sOV  = (int*)(smem + 24576);                       // [24K, 40.5K)
    int* sCnt = (int*)(smem + 41472);                       // 512B
    unsigned short* obuf = (unsigned short*)(smem + 41984); // 34816B
    const int t = threadIdx.x;
    // XCD-aware swizzle (speed heuristic only; correctness order-free)
    const int b = blockIdx.x;
    const int xcd = b & 7, j = b >> 3;
    const int bf = j & 7;
    const int bm = (j >> 3) * 8 + xcd;
    const int wave = t >> 6, lane = t & 63;
    const int wm = wave & 1, wn = wave >> 1;
    const int lr = lane & 15, quad = lane >> 4;
    const int srow = wave * 16 + (lane >> 2), scol = (lane & 3) << 3;
    const unsigned short* gA = A   + (size_t)(bm * 128 + srow) * DM + scol;
    const unsigned short* gC = Bct + (size_t)(bf * 128 + srow) * DM + scol;
    const unsigned short* gG = Bgt + (size_t)(bf * 128 + srow) * DM + scol;
    unsigned short* lA = &As[wave * 16 * LDSS];
    unsigned short* lC = &Bcs[wave * 16 * LDSS];
    unsigned short* lG = &Bgs[wave * 16 * LDSS];

    if (t < 128) sCnt[t] = counts[bm * 128 + t];

    floatx4 accc[4][2], accg[4][2];
    #pragma unroll
    for (int i = 0; i < 4; i++)
        #pragma unroll
        for (int jj = 0; jj < 2; jj++) { accc[i][jj] = (floatx4)0.0f; accg[i][jj] = (floatx4)0.0f; }

    for (int k0 = 0; k0 < DM; k0 += 32) {
        __syncthreads();            // covers sCnt stage (1st iter) + prior ds_reads
        g2lds16(gA + k0, lA);
        g2lds16(gC + k0, lC);
        g2lds16(gG + k0, lG);
        __syncthreads();
        bf16x8 af[4], bcf[2], bgf[2];
        #pragma unroll
        for (int mi = 0; mi < 4; mi++)
            af[mi] = *(const bf16x8*)&As[(wm * 64 + mi * 16 + lr) * LDSS + quad * 8];
        #pragma unroll
        for (int ni = 0; ni < 2; ni++) {
            bcf[ni] = *(const bf16x8*)&Bcs[(wn * 32 + ni * 16 + lr) * LDSS + quad * 8];
            bgf[ni] = *(const bf16x8*)&Bgs[(wn * 32 + ni * 16 + lr) * LDSS + quad * 8];
        }
        #pragma unroll
        for (int mi = 0; mi < 4; mi++)
            #pragma unroll
            for (int ni = 0; ni < 2; ni++) {
                accc[mi][ni] = __builtin_amdgcn_mfma_f32_16x16x32_bf16(af[mi], bcf[ni], accc[mi][ni], 0, 0, 0);
                accg[mi][ni] = __builtin_amdgcn_mfma_f32_16x16x32_bf16(af[mi], bgf[ni], accg[mi][ni], 0, 0, 0);
            }
    }

    // ---- phase 1: consume accumulators NOW (frees 64 AGPR for the gather).
    // out = g*tv + (1-g)*cla; only tv needs the gather. Precompute g and
    // C=(1-g)*cla, packed 2xbf16 per u32. bc/bg direct from global (L2-hot;
    // par is not staged yet). Pure register work -> overlaps other waves'
    // final K-step MFMA. All gc indexing is compile-time (rule #20).
    unsigned int gc[4][2][4];
    {
        float bcv[2], bgv[2];
        #pragma unroll
        for (int ni = 0; ni < 2; ni++) {
            int gf = bf * 128 + wn * 32 + ni * 16 + lr;
            bcv[ni] = bc[gf];
            bgv[ni] = bg[gf];
        }
        #pragma unroll
        for (int mi = 0; mi < 4; mi++)
            #pragma unroll
            for (int ni = 0; ni < 2; ni++)
                #pragma unroll
                for (int r = 0; r < 4; r++) {
                    float cpre = accc[mi][ni][r] + bcv[ni];
                    float gpre = accg[mi][ni][r] + bgv[ni];
                    float g = sigm(gpre);
                    float cla = gelu_f(cpre);
                    unsigned short gh = f2bf(g);
                    float gq = bf2f(gh);                 // post-rounding g: keeps blend convex
                    unsigned short ch = f2bf((1.0f - gq) * cla);
                    gc[mi][ni][r] = ((unsigned int)gh << 16) | (unsigned int)ch;
                }
    }
    __syncthreads();   // staging bufs dead; overlay par

    // ---- stage epilogue params into LDS: par[fl*36 + {0..7 slx, 8..15 ofx,
    //      16..23 slc, 24..31 ofc, 32 bt, 33 s, 34 bc, 35 bg}]
    for (int e = t; e < 1024; e += 512) {
        int ff = e >> 3, w = e & 7;
        int gf = (bf * 128 + ff) * 8 + w;
        par[ff * 36 + w]      = slx[gf];
        par[ff * 36 + 8 + w]  = ofx[gf];
        par[ff * 36 + 16 + w] = slc[gf];
        par[ff * 36 + 24 + w] = ofc[gf];
    }
    if (t < 128) {
        int gf = bf * 128 + t;
        par[t * 36 + 32] = bt[gf];
        par[t * 36 + 33] = s[gf];
        par[t * 36 + 34] = bc[gf];
        par[t * 36 + 35] = bg[gf];
    }
    // ---- stage packed candidate meta (pre-padded: d=0, val=-1e30 -> branchless)
    const int PADV = (int)(((unsigned int)f2bf(-1e30f)) << 16);
    for (int e = t; e < 128 * KMAX; e += 512) {
        int m = e >> 5, k = e & 31;
        int c = sCnt[m];
        int pk = PADV;
        if (k < (c < KMAX ? c : KMAX)) {
            int d  = cidx[(size_t)(bm * 128 + m) * KMAX + k];
            float v = cval[(size_t)(bm * 128 + m) * KMAX + k];
            pk = (int)(((unsigned int)f2bf(v)) << 16) | d;
        }
        sOV[m * KPAD + k] = pk;
    }
    __syncthreads();

    // ---- phase 2: tropical z gather (2x-unrolled) + convex/concave + blend ----
    // C/D layout col=lane&15, row=quad*4+r  [verified m89/m91]
    const int f0 = bf * 128 + wn * 32 + lr;    // ni=0 global f; ni=1 is +16
    #pragma unroll
    for (int mi = 0; mi < 4; mi++) {
        const int mb = wm * 64 + mi * 16 + quad * 4;   // local m of r=0
        int c0 = sCnt[mb], c1 = sCnt[mb + 1], c2 = sCnt[mb + 2], c3 = sCnt[mb + 3];
        int k0c = c0 < KMAX ? c0 : KMAX, k1c = c1 < KMAX ? c1 : KMAX;
        int k2c = c2 < KMAX ? c2 : KMAX, k3c = c3 < KMAX ? c3 : KMAX;
        int km = max(max(k0c, k1c), max(k2c, k3c));
        int km2 = (km + 1) & ~1;          // even trip; sOV slots < 32 are PADV-padded
        // z packed across the (f0, f0+16) column pair: .x = ni0, .y = ni1
        floatx2 zp0 = { -1e30f, -1e30f }, zp1 = zp0, zp2 = zp0, zp3 = zp0;
        for (int k = 0; k < km2; k += 2) {
            int p0 = sOV[(mb + 0) * KPAD + k];
            int p1 = sOV[(mb + 1) * KPAD + k];
            int p2 = sOV[(mb + 2) * KPAD + k];
            int p3 = sOV[(mb + 3) * KPAD + k];
            int q0 = sOV[(mb + 0) * KPAD + k + 1];
            int q1 = sOV[(mb + 1) * KPAD + k + 1];
            int q2 = sOV[(mb + 2) * KPAD + k + 1];
            int q3 = sOV[(mb + 3) * KPAD + k + 1];
            const float* r0 = WtT + ((p0 & 0xFFFF) << 10) + f0;
            const float* r1 = WtT + ((p1 & 0xFFFF) << 10) + f0;
            const float* r2 = WtT + ((p2 & 0xFFFF) << 10) + f0;
            const float* r3 = WtT + ((p3 & 0xFFFF) << 10) + f0;
            const float* t0 = WtT + ((q0 & 0xFFFF) << 10) + f0;
            const float* t1 = WtT + ((q1 & 0xFFFF) << 10) + f0;
            const float* t2 = WtT + ((q2 & 0xFFFF) << 10) + f0;
            const float* t3 = WtT + ((q3 & 0xFFFF) << 10) + f0;
            floatx2 w0 = { r0[0], r0[16] };
            floatx2 w1 = { r1[0], r1[16] };
            floatx2 w2 = { r2[0], r2[16] };
            floatx2 w3 = { r3[0], r3[16] };
            floatx2 u0 = { t0[0], t0[16] };
            floatx2 u1 = { t1[0], t1[16] };
            floatx2 u2 = { t2[0], t2[16] };
            floatx2 u3 = { t3[0], t3[16] };
            float s0 = __int_as_float(p0 & 0xFFFF0000);
            float s1 = __int_as_float(p1 & 0xFFFF0000);
            float s2 = __int_as_float(p2 & 0xFFFF0000);
            float s3 = __int_as_float(p3 & 0xFFFF0000);
            float e0 = __int_as_float(q0 & 0xFFFF0000);
            float e1 = __int_as_float(q1 & 0xFFFF0000);
            float e2 = __int_as_float(q2 & 0xFFFF0000);
            float e3 = __int_as_float(q3 & 0xFFFF0000);
            floatx2 v0 = { s0, s0 }, v1 = { s1, s1 }, v2 = { s2, s2 }, v3 = { s3, s3 };
            floatx2 y0 = { e0, e0 }, y1 = { e1, e1 }, y2 = { e2, e2 }, y3 = { e3, e3 };
            zp0 = PKMAX(PKMAX(zp0, v0 + w0), y0 + u0);
            zp1 = PKMAX(PKMAX(zp1, v1 + w1), y1 + u1);
            zp2 = PKMAX(PKMAX(zp2, v2 + w2), y2 + u2);
            zp3 = PKMAX(PKMAX(zp3, v3 + w3), y3 + u3);
        }
        // exact fallback (count > KMAX, ~never): full 256-d scan
        if (c0 > KMAX || c1 > KMAX || c2 > KMAX || c3 > KMAX) {
            float za[4] = { zp0.x, zp1.x, zp2.x, zp3.x };
            float zb[4] = { zp0.y, zp1.y, zp2.y, zp3.y };
            int cc[4] = { c0, c1, c2, c3 };
            #pragma unroll 1
            for (int r = 0; r < 4; r++) if (cc[r] > KMAX) {
                const float* xr = x + (size_t)(bm * 128 + mb + r) * DM;
                float ma = -1e30f, mbv = -1e30f;
                for (int d = 0; d < DM; d++) {
                    float xv = xr[d];
                    ma  = fmaxf(ma,  xv + WtT[d * NF + f0]);
                    mbv = fmaxf(mbv, xv + WtT[d * NF + f0 + 16]);
                }
                za[r] = ma; zb[r] = mbv;
            }
            zp0.x = za[0]; zp1.x = za[1]; zp2.x = za[2]; zp3.x = za[3];
            zp0.y = zb[0]; zp1.y = zb[1]; zp2.y = zb[2]; zp3.y = zb[3];
        }
        #pragma unroll
        for (int ni = 0; ni < 2; ni++) {
            const int fl = wn * 32 + ni * 16 + lr;
            const float* pp = par + fl * 36;
            float4 a0 = *(const float4*)(pp),      a1 = *(const float4*)(pp + 4);
            float4 b0 = *(const float4*)(pp + 8),  b1 = *(const float4*)(pp + 12);
            float4 cc0 = *(const float4*)(pp + 16), cc1 = *(const float4*)(pp + 20);
            float4 d0 = *(const float4*)(pp + 24), d1 = *(const float4*)(pp + 28);
            float4 sc = *(const float4*)(pp + 32);  // bt, s (bc/bg consumed in phase 1)
            // segment-pair packing for the PWL hulls (v_pk_fma/pk_max/pk_min) [r3-verified]
            floatx2 sA0 = { a0.x, a0.y }, sA1 = { a0.z, a0.w };
            floatx2 sA2 = { a1.x, a1.y }, sA3 = { a1.z, a1.w };
            floatx2 oA0 = { b0.x, b0.y }, oA1 = { b0.z, b0.w };
            floatx2 oA2 = { b1.x, b1.y }, oA3 = { b1.z, b1.w };
            floatx2 sC0 = { cc0.x, cc0.y }, sC1 = { cc0.z, cc0.w };
            floatx2 sC2 = { cc1.x, cc1.y }, sC3 = { cc1.z, cc1.w };
            floatx2 oC0 = { d0.x, d0.y }, oC1 = { d0.z, d0.w };
            floatx2 oC2 = { d1.x, d1.y }, oC3 = { d1.z, d1.w };
            float zr[4];
            if (ni == 0) { zr[0] = zp0.x; zr[1] = zp1.x; zr[2] = zp2.x; zr[3] = zp3.x; }
            else         { zr[0] = zp0.y; zr[1] = zp1.y; zr[2] = zp2.y; zr[3] = zp3.y; }
            #pragma unroll
            for (int r = 0; r < 4; r++) {
                float zv = zr[r] + sc.x;
                floatx2 zz = { zv, zv };
                floatx2 tx = PKMAX(PKMAX(PKFMA(zz, sA0, oA0), PKFMA(zz, sA1, oA1)),
                                   PKMAX(PKFMA(zz, sA2, oA2), PKFMA(zz, sA3, oA3)));
                float cvx = fmaxf(tx.x, tx.y);
                floatx2 tn = PKMIN(PKMIN(PKFMA(zz, sC0, oC0), PKFMA(zz, sC1, oC1)),
                                   PKMIN(PKFMA(zz, sC2, oC2), PKFMA(zz, sC3, oC3)));
                float ccv = fminf(tn.x, tn.y);
                float tv = sc.y * cvx + (1.0f - sc.y) * ccv;
                unsigned int gcv = gc[mi][ni][r];
                float g = bf2f((unsigned short)(gcv >> 16));
                float C = bf2f((unsigned short)(gcv & 0xFFFFu));
                obuf[(mb + r) * OSTR + fl] = f2bf(g * tv + C);
            }
        }
    }
    __syncthreads();   // full 128x128 obuf tile complete
    // cooperative coalesced store: 256B contiguous per row-segment
    #pragma unroll
    for (int e = t; e < 128 * 16; e += 512) {
        int row = e >> 4, c8 = (e & 15) << 3;
        ushort8 v = *(const ushort8*)&obuf[row * OSTR + c8];
        *(ushort8*)&fused[(size_t)(bm * 128 + row) * NF + bf * 128 + c8] = v;
    }
}

// ------------------------------------------------- kernel 5: GEMM2 (fused@Wd + bd) (r0 verbatim)
#define LDS2 64
__global__ __launch_bounds__(512, 4) void gemm2_kernel(
    const unsigned short* __restrict__ A,  // fused [T][1024]
    const unsigned short* __restrict__ Bt, // WdT [256][1024]
    const float* __restrict__ bd, float* __restrict__ out) {
    __shared__ __align__(16) unsigned short As[128 * LDS2];
    __shared__ __align__(16) unsigned short Bs[128 * LDS2];
    const int t = threadIdx.x;
    const int b = blockIdx.x;
    const int xcd = b & 7, j = b >> 3;
    const int bn = j & 1;
    const int bm = (j >> 1) * 8 + xcd;
    const int wave = t >> 6, lane = t & 63;
    const int wm = wave & 1, wn = wave >> 1;
    const int lr = lane & 15, quad = lane >> 4;
    const int srow = wave * 8 + (lane >> 3), scol = (lane & 7) << 3;  // 64 rows/issue
    const unsigned short* gA = A  + (size_t)(bm * 128 + srow) * NF + scol;
    const unsigned short* gB = Bt + (size_t)(bn * 128 + srow) * NF + scol;
    unsigned short* lA = &As[wave * 8 * LDS2];
    unsigned short* lB = &Bs[wave * 8 * LDS2];

    floatx4 acc[4][2];
    #pragma unroll
    for (int i = 0; i < 4; i++)
        #pragma unroll
        for (int jj = 0; jj < 2; jj++) acc[i][jj] = (floatx4)0.0f;

    for (int k0 = 0; k0 < NF; k0 += 64) {
        __syncthreads();
        g2lds16(gA + k0, lA);
        g2lds16(gA + k0 + (size_t)64 * NF, lA + 64 * LDS2);
        g2lds16(gB + k0, lB);
        g2lds16(gB + k0 + (size_t)64 * NF, lB + 64 * LDS2);
        __syncthreads();
        #pragma unroll
        for (int ks = 0; ks < 2; ks++) {
            bf16x8 af[4], bf_[2];
            #pragma unroll
            for (int mi = 0; mi < 4; mi++)
                af[mi] = *(const bf16x8*)&As[(wm * 64 + mi * 16 + lr) * LDS2 + ks * 32 + quad * 8];
            #pragma unroll
            for (int ni = 0; ni < 2; ni++)
                bf_[ni] = *(const bf16x8*)&Bs[(wn * 32 + ni * 16 + lr) * LDS2 + ks * 32 + quad * 8];
            #pragma unroll
            for (int mi = 0; mi < 4; mi++)
                #pragma unroll
                for (int ni = 0; ni < 2; ni++)
                    acc[mi][ni] = __builtin_amdgcn_mfma_f32_16x16x32_bf16(af[mi], bf_[ni], acc[mi][ni], 0, 0, 0);
        }
    }
    #pragma unroll
    for (int mi = 0; mi < 4; mi++)
        #pragma unroll
        for (int ni = 0; ni < 2; ni++) {
            int n = bn * 128 + wn * 32 + ni * 16 + lr;
            float bdv = bd[n];
            #pragma unroll
            for (int r = 0; r < 4; r++) {
                int m = bm * 128 + wm * 64 + mi * 16 + quad * 4 + r;
                out[m * DM + n] = acc[mi][ni][r] + bdv;
            }
        }
}

// ------------------------------------------------------------- launcher (r0 verbatim)
extern "C" void kernel_launch(void* const* d_in, const int* in_sizes, int n_in,
                              void* d_out, int out_size, void* d_ws, size_t ws_size,
                              hipStream_t stream) {
    const float* x     = (const float*)d_in[0];
    const float* Wt    = (const float*)d_in[1];
    const float* bt    = (const float*)d_in[2];
    const float* slx   = (const float*)d_in[3];
    const float* ofx   = (const float*)d_in[4];
    const float* slc   = (const float*)d_in[5];
    const float* ofc   = (const float*)d_in[6];
    const float* alpha = (const float*)d_in[7];
    const float* Wc    = (const float*)d_in[8];
    const float* bc    = (const float*)d_in[9];
    const float* Wg    = (const float*)d_in[10];
    const float* bg    = (const float*)d_in[11];
    const float* Wd    = (const float*)d_in[12];
    const float* bd    = (const float*)d_in[13];
    float* out = (float*)d_out;
    char* ws = (char*)d_ws;

    unsigned int* slot = (unsigned int*)(ws + O_SLOT);
    float* s           = (float*)(ws + O_S);
    unsigned short* Wct = (unsigned short*)(ws + O_WCT);
    unsigned short* Wgt = (unsigned short*)(ws + O_WGT);
    unsigned short* WdT = (unsigned short*)(ws + O_WDT);
    float* WtT          = (float*)(ws + O_WTT);
    unsigned short* xbf = (unsigned short*)(ws + O_XBF);
    int* counts         = (int*)(ws + O_CNT);
    int* cidx           = (int*)(ws + O_CIDX);
    float* cval         = (float*)(ws + O_CVAL);
    unsigned short* fused = (unsigned short*)(ws + O_FUSD);

    pack_kernel<<<1024, 256, 0, stream>>>(Wt, alpha, Wc, Wg, Wd, Wct, Wgt, WdT, WtT, s, slot);
    minmax_kernel<<<128, 256, 0, stream>>>(Wt, slot);
    cand_kernel<<<TTOK, 256, 0, stream>>>(x, slot, xbf, counts, cidx, cval);
    gemm1_kernel<<<2048, 512, 0, stream>>>(
        xbf, Wct, Wgt, bc, bg, counts, cidx, cval, x, WtT, bt,
        slx, ofx, slc, ofc, s, fused);
    gemm2_kernel<<<512, 512, 0, stream>>>(fused, WdT, bd, out);
}

// Round 7
// 301.821 us; speedup vs baseline: 1.1429x; 1.1429x over previous
//
#include <hip/hip_runtime.h>

// ---------------------------------------------------------------- constants
#define TTOK 32768
#define DM   256
#define NF   1024
#define KMAX 32

typedef __attribute__((ext_vector_type(8))) unsigned short ushort8;
typedef __attribute__((ext_vector_type(8))) __bf16 bf16x8;
typedef __attribute__((ext_vector_type(4))) float floatx4;
typedef __attribute__((ext_vector_type(2))) float floatx2;

// packed f32 math (lowers to v_pk_fma_f32 / v_pk_max_f32 / v_pk_min_f32)
#define PKFMA(a,b,c) __builtin_elementwise_fma(a,b,c)
#define PKMAX(a,b)   __builtin_elementwise_max(a,b)
#define PKMIN(a,b)   __builtin_elementwise_min(a,b)

// workspace offsets (all 256B aligned)
constexpr size_t O_SLOT = 0;                                   // 1 uint (max|Wt|)
constexpr size_t O_S    = 256;                                 // 1024 f32 sigmoid(alpha)
constexpr size_t O_WCT  = O_S    + 4096;                       // Wc^T  [1024][256] bf16
constexpr size_t O_WGT  = O_WCT  + (size_t)NF*DM*2;            // Wg^T  [1024][256] bf16
constexpr size_t O_WDT  = O_WGT  + (size_t)NF*DM*2;            // Wd^T  [256][1024] bf16
constexpr size_t O_WTT  = O_WDT  + (size_t)DM*NF*2;            // Wt^T  PAIR-INTERLEAVED [256][1024] f32
constexpr size_t O_XBF  = O_WTT  + (size_t)DM*NF*4;            // x bf16 [T][256]
constexpr size_t O_CNT  = O_XBF  + (size_t)TTOK*DM*2;          // counts [T]
constexpr size_t O_CIDX = O_CNT  + (size_t)TTOK*4;             // cand d (raw) [T][KMAX]
constexpr size_t O_CVAL = O_CIDX + (size_t)TTOK*KMAX*4;        // cand val [T][KMAX]
constexpr size_t O_FUSD = O_CVAL + (size_t)TTOK*KMAX*4;        // fused bf16 [T][1024]

__device__ __forceinline__ float bf2f(unsigned short u) {
    union { unsigned int i; float f; } c; c.i = ((unsigned int)u) << 16; return c.f;
}
__device__ __forceinline__ unsigned short f2bf(float v) {
    union { float f; unsigned int i; } c; c.f = v;
    unsigned int b = c.i;
    return (unsigned short)((b + 0x7FFFu + ((b >> 16) & 1u)) >> 16);
}
__device__ __forceinline__ float sigm(float z) { return 1.0f / (1.0f + __expf(-z)); }
// tanh-gelu: max |diff| vs exact erf-gelu ~3e-3, far under 0.266 tolerance
__device__ __forceinline__ float gelu_f(float x) {
    return x * sigm(1.59576912f * (x + 0.044715f * x * x * x));
}
// async global->LDS, 16B per lane; lds dest = wave-uniform base + lane*16 [m97/m104]
__device__ __forceinline__ void g2lds16(const unsigned short* g, unsigned short* l) {
    __builtin_amdgcn_global_load_lds((const __attribute__((address_space(1))) unsigned int*)g,
                                     (__attribute__((address_space(3))) unsigned int*)l, 16, 0, 0);
}

// ------------------------------------------------- kernel 1: pack weights
// r7: WtT is now PAIR-INTERLEAVED so the gemm1 gather reads (W[d][f],
// W[d][f+16]) as ONE float2: for f=32a+b (b<16) -> idx d*1024+32a+2b;
// for f=32a+16+b -> idx d*1024+32a+2b+1. Bijective within each 32-block.
// Everything else r0 verbatim.
__global__ void pack_kernel(const float* __restrict__ Wt, const float* __restrict__ alpha,
                            const float* __restrict__ Wc, const float* __restrict__ Wg,
                            const float* __restrict__ Wd,
                            unsigned short* __restrict__ Wct, unsigned short* __restrict__ Wgt,
                            unsigned short* __restrict__ WdT, float* __restrict__ WtT,
                            float* __restrict__ s, unsigned int* __restrict__ slot) {
    int e = blockIdx.x * 256 + threadIdx.x;
    if (e == 0) *slot = 0u;
    { int f = e >> 8, k = e & 255;           // Wc/Wg are [256][1024]
      Wct[e] = f2bf(Wc[k * NF + f]);
      Wgt[e] = f2bf(Wg[k * NF + f]); }
    { int n = e >> 10, k = e & 1023;         // Wd is [1024][256]
      WdT[e] = f2bf(Wd[k * DM + n]); }
    { int d = e >> 10, f = e & 1023;         // Wt is [1024][256]
      int idx = (d << 10) + ((f >> 5) << 5) + ((f & 15) << 1) + ((f >> 4) & 1);
      WtT[idx] = Wt[f * DM + d]; }
    if (e < NF) s[e] = sigm(alpha[e]);
}

// ------------------------------------------------- kernel 2: max|Wt| reduce (r0 verbatim)
__global__ void minmax_kernel(const float* __restrict__ Wt, unsigned int* __restrict__ slot) {
    int g = blockIdx.x * 256 + threadIdx.x;
    float lm = 0.0f;
    for (int i = g; i < NF * DM; i += 128 * 256) lm = fmaxf(lm, fabsf(Wt[i]));
    #pragma unroll
    for (int o = 32; o > 0; o >>= 1) lm = fmaxf(lm, __shfl_xor(lm, o));
    if ((threadIdx.x & 63) == 0) atomicMax(slot, __float_as_uint(lm)); // |w|>=0: uint order ok
}

// ------------------------------------------------- kernel 3: candidates + x->bf16 (r0 verbatim)
__global__ void cand_kernel(const float* __restrict__ x, const unsigned int* __restrict__ slot,
                            unsigned short* __restrict__ xbf, int* __restrict__ counts,
                            int* __restrict__ cidx, float* __restrict__ cval) {
    int i = blockIdx.x, t = threadIdx.x;
    float v = x[i * DM + t];
    xbf[i * DM + t] = f2bf(v);
    float m = v;
    #pragma unroll
    for (int o = 32; o > 0; o >>= 1) m = fmaxf(m, __shfl_xor(m, o));
    __shared__ float wm[4];
    __shared__ int cnt;
    __shared__ int sidx[KMAX];
    __shared__ float sval[KMAX];
    if ((t & 63) == 0) wm[t >> 6] = m;
    if (t == 0) cnt = 0;
    __syncthreads();
    float xmax = fmaxf(fmaxf(wm[0], wm[1]), fmaxf(wm[2], wm[3]));
    float delta = 2.0f * __uint_as_float(*slot);   // >= Wmax - Wmin : exact exclusion bound
    float thr = xmax - delta;
    if (v >= thr) {
        int p = atomicAdd(&cnt, 1);
        if (p < KMAX) { sidx[p] = t; sval[p] = v; }   // raw d index
    }
    __syncthreads();
    int c = cnt;
    if (t == 0) counts[i] = c;
    if (t < (c < KMAX ? c : KMAX)) {
        cidx[i * KMAX + t] = sidx[t];
        cval[i * KMAX + t] = sval[t];
    }
}

// ------------------------------------------------- kernel 4: fused GEMM1
// (x@Wc, x@Wg) MFMA + tropical max-plus + convex/concave + gate blend.
// 128x128 tile, BK=32, 512 thr (8 waves 2Mx4F, wave 64x32 dual-output).
// Ledger:
//  r7(128x64+reg-diet): spills+L2 thrash. REVERTED.
//  r8(DB loop): no win. r8(pre-loop prestage): spills. DROPPED.
//  r9(packed epilogue): gemm1 190->178. KEPT (r3 text). r10(floatx2-direct
//    par): correctness FAIL. REVERTED.
//  r5(r0 structure + r3 pk epilogue): VERIFIED 150us, WRITE=65536 exactly.
//  r6(phase-split + 2x gather unroll): WRITE 206MB, 203us. REVERTED. Root
//    cause: freed AGPRs can't fund arch-VGPR pressure -- launch_bounds(512,4)
//    pins arch side at 64 and gc[32]+unroll overflowed to scratch. LESSON:
//    zero headroom for extra long-lived epilogue state; breadth-via-registers
//    is a dead end at this occupancy.
//  r7 (this): gather transaction diet, zero extra registers -- WtT pair-
//    interleaved so each row's (f0, f0+16) pair is ONE float2 load (8->4
//    global loads per k-iter, half the addr arith). Same values, same
//    latency chain, half the transactions.
//    Falsifiable: WRITE=65536 exactly, FETCH ~31MB, gemm1 <= 145us.
#define LDSS 32   // ushorts per LDS row, no pad (wave-uniform-base DMA, m104)
#define KPAD 33
#define OSTR 136  // obuf row stride in ushorts (272B, 16q+4r+col bank spread)
__global__ __launch_bounds__(512, 4) void gemm1_kernel(
    const unsigned short* __restrict__ A,   // xbf [T][256]
    const unsigned short* __restrict__ Bct, // [1024][256]
    const unsigned short* __restrict__ Bgt, // [1024][256]
    const float* __restrict__ bc, const float* __restrict__ bg,
    const int* __restrict__ counts, const int* __restrict__ cidx,
    const float* __restrict__ cval, const float* __restrict__ x,
    const float* __restrict__ WtT, const float* __restrict__ bt,
    const float* __restrict__ slx, const float* __restrict__ ofx,
    const float* __restrict__ slc, const float* __restrict__ ofc,
    const float* __restrict__ s, unsigned short* __restrict__ fused) {
    __shared__ __align__(16) char smem[76800];
    unsigned short* As  = (unsigned short*)smem;            // [0, 8K)     K-loop
    unsigned short* Bcs = As + 4096;                        // [8K, 16K)   K-loop
    unsigned short* Bgs = As + 8192;                        // [16K, 24K)  K-loop
    float* par = (float*)smem;                              // [0, 18K)    epilogue (overlay)
    int* sOV  = (int*)(smem + 24576);                       // [24K, 40.5K)
    int* sCnt = (int*)(smem + 41472);                       // 512B
    unsigned short* obuf = (unsigned short*)(smem + 41984); // 34816B
    const int t = threadIdx.x;
    // XCD-aware swizzle (speed heuristic only; correctness order-free)
    const int b = blockIdx.x;
    const int xcd = b & 7, j = b >> 3;
    const int bf = j & 7;
    const int bm = (j >> 3) * 8 + xcd;
    const int wave = t >> 6, lane = t & 63;
    const int wm = wave & 1, wn = wave >> 1;
    const int lr = lane & 15, quad = lane >> 4;
    const int srow = wave * 16 + (lane >> 2), scol = (lane & 3) << 3;
    const unsigned short* gA = A   + (size_t)(bm * 128 + srow) * DM + scol;
    const unsigned short* gC = Bct + (size_t)(bf * 128 + srow) * DM + scol;
    const unsigned short* gG = Bgt + (size_t)(bf * 128 + srow) * DM + scol;
    unsigned short* lA = &As[wave * 16 * LDSS];
    unsigned short* lC = &Bcs[wave * 16 * LDSS];
    unsigned short* lG = &Bgs[wave * 16 * LDSS];

    if (t < 128) sCnt[t] = counts[bm * 128 + t];

    floatx4 accc[4][2], accg[4][2];
    #pragma unroll
    for (int i = 0; i < 4; i++)
        #pragma unroll
        for (int jj = 0; jj < 2; jj++) { accc[i][jj] = (floatx4)0.0f; accg[i][jj] = (floatx4)0.0f; }

    for (int k0 = 0; k0 < DM; k0 += 32) {
        __syncthreads();            // covers sCnt stage (1st iter) + prior ds_reads
        g2lds16(gA + k0, lA);
        g2lds16(gC + k0, lC);
        g2lds16(gG + k0, lG);
        __syncthreads();
        bf16x8 af[4], bcf[2], bgf[2];
        #pragma unroll
        for (int mi = 0; mi < 4; mi++)
            af[mi] = *(const bf16x8*)&As[(wm * 64 + mi * 16 + lr) * LDSS + quad * 8];
        #pragma unroll
        for (int ni = 0; ni < 2; ni++) {
            bcf[ni] = *(const bf16x8*)&Bcs[(wn * 32 + ni * 16 + lr) * LDSS + quad * 8];
            bgf[ni] = *(const bf16x8*)&Bgs[(wn * 32 + ni * 16 + lr) * LDSS + quad * 8];
        }
        #pragma unroll
        for (int mi = 0; mi < 4; mi++)
            #pragma unroll
            for (int ni = 0; ni < 2; ni++) {
                accc[mi][ni] = __builtin_amdgcn_mfma_f32_16x16x32_bf16(af[mi], bcf[ni], accc[mi][ni], 0, 0, 0);
                accg[mi][ni] = __builtin_amdgcn_mfma_f32_16x16x32_bf16(af[mi], bgf[ni], accg[mi][ni], 0, 0, 0);
            }
    }
    __syncthreads();   // staging bufs dead; overlay par

    // ---- stage epilogue params into LDS: par[fl*36 + {0..7 slx, 8..15 ofx,
    //      16..23 slc, 24..31 ofc, 32 bt, 33 s, 34 bc, 35 bg}]
    for (int e = t; e < 1024; e += 512) {
        int ff = e >> 3, w = e & 7;
        int gf = (bf * 128 + ff) * 8 + w;
        par[ff * 36 + w]      = slx[gf];
        par[ff * 36 + 8 + w]  = ofx[gf];
        par[ff * 36 + 16 + w] = slc[gf];
        par[ff * 36 + 24 + w] = ofc[gf];
    }
    if (t < 128) {
        int gf = bf * 128 + t;
        par[t * 36 + 32] = bt[gf];
        par[t * 36 + 33] = s[gf];
        par[t * 36 + 34] = bc[gf];
        par[t * 36 + 35] = bg[gf];
    }
    // ---- stage packed candidate meta (pre-padded: d=0, val=-1e30 -> branchless)
    const int PADV = (int)(((unsigned int)f2bf(-1e30f)) << 16);
    for (int e = t; e < 128 * KMAX; e += 512) {
        int m = e >> 5, k = e & 31;
        int c = sCnt[m];
        int pk = PADV;
        if (k < (c < KMAX ? c : KMAX)) {
            int d  = cidx[(size_t)(bm * 128 + m) * KMAX + k];
            float v = cval[(size_t)(bm * 128 + m) * KMAX + k];
            pk = (int)(((unsigned int)f2bf(v)) << 16) | d;
        }
        sOV[m * KPAD + k] = pk;
    }
    __syncthreads();

    // ---- fused epilogue: tropical z + convex/concave + gate blend ----
    // C/D layout col=lane&15, row=quad*4+r  [verified m89/m91]
    const int f0 = bf * 128 + wn * 32 + lr;    // ni=0 global f; ni=1 is +16
    // pair-interleaved WtT: float2 at row*1024 + pofs = (W[f0], W[f0+16])
    const int pofs = ((f0 >> 5) << 5) + ((f0 & 15) << 1);
    #pragma unroll
    for (int mi = 0; mi < 4; mi++) {
        const int mb = wm * 64 + mi * 16 + quad * 4;   // local m of r=0
        int c0 = sCnt[mb], c1 = sCnt[mb + 1], c2 = sCnt[mb + 2], c3 = sCnt[mb + 3];
        int k0c = c0 < KMAX ? c0 : KMAX, k1c = c1 < KMAX ? c1 : KMAX;
        int k2c = c2 < KMAX ? c2 : KMAX, k3c = c3 < KMAX ? c3 : KMAX;
        int km = max(max(k0c, k1c), max(k2c, k3c));
        // z packed across the (f0, f0+16) column pair: .x = ni0, .y = ni1  [r3-verified]
        floatx2 zp0 = { -1e30f, -1e30f }, zp1 = zp0, zp2 = zp0, zp3 = zp0;
        for (int k = 0; k < km; k++) {
            int p0 = sOV[(mb + 0) * KPAD + k];
            int p1 = sOV[(mb + 1) * KPAD + k];
            int p2 = sOV[(mb + 2) * KPAD + k];
            int p3 = sOV[(mb + 3) * KPAD + k];
            floatx2 w0 = *(const floatx2*)(WtT + ((p0 & 0xFFFF) << 10) + pofs);
            floatx2 w1 = *(const floatx2*)(WtT + ((p1 & 0xFFFF) << 10) + pofs);
            floatx2 w2 = *(const floatx2*)(WtT + ((p2 & 0xFFFF) << 10) + pofs);
            floatx2 w3 = *(const floatx2*)(WtT + ((p3 & 0xFFFF) << 10) + pofs);
            float s0 = __int_as_float(p0 & 0xFFFF0000);
            float s1 = __int_as_float(p1 & 0xFFFF0000);
            float s2 = __int_as_float(p2 & 0xFFFF0000);
            float s3 = __int_as_float(p3 & 0xFFFF0000);
            floatx2 v0 = { s0, s0 }, v1 = { s1, s1 }, v2 = { s2, s2 }, v3 = { s3, s3 };
            zp0 = PKMAX(zp0, v0 + w0);
            zp1 = PKMAX(zp1, v1 + w1);
            zp2 = PKMAX(zp2, v2 + w2);
            zp3 = PKMAX(zp3, v3 + w3);
        }
        // exact fallback (count > KMAX, ~never): full 256-d scan (pair reads)
        if (c0 > KMAX || c1 > KMAX || c2 > KMAX || c3 > KMAX) {
            float za[4] = { zp0.x, zp1.x, zp2.x, zp3.x };
            float zb[4] = { zp0.y, zp1.y, zp2.y, zp3.y };
            int cc[4] = { c0, c1, c2, c3 };
            #pragma unroll 1
            for (int r = 0; r < 4; r++) if (cc[r] > KMAX) {
                const float* xr = x + (size_t)(bm * 128 + mb + r) * DM;
                float ma = -1e30f, mbv = -1e30f;
                for (int d = 0; d < DM; d++) {
                    float xv = xr[d];
                    floatx2 wp = *(const floatx2*)(WtT + (d << 10) + pofs);
                    ma  = fmaxf(ma,  xv + wp.x);
                    mbv = fmaxf(mbv, xv + wp.y);
                }
                za[r] = ma; zb[r] = mbv;
            }
            zp0.x = za[0]; zp1.x = za[1]; zp2.x = za[2]; zp3.x = za[3];
            zp0.y = zb[0]; zp1.y = zb[1]; zp2.y = zb[2]; zp3.y = zb[3];
        }
        #pragma unroll
        for (int ni = 0; ni < 2; ni++) {
            const int fl = wn * 32 + ni * 16 + lr;
            const float* pp = par + fl * 36;
            float4 a0 = *(const float4*)(pp),      a1 = *(const float4*)(pp + 4);
            float4 b0 = *(const float4*)(pp + 8),  b1 = *(const float4*)(pp + 12);
            float4 cc0 = *(const float4*)(pp + 16), cc1 = *(const float4*)(pp + 20);
            float4 d0 = *(const float4*)(pp + 24), d1 = *(const float4*)(pp + 28);
            float4 sc = *(const float4*)(pp + 32);  // bt, s, bc, bg
            // segment-pair packing for the PWL hulls (v_pk_fma/pk_max/pk_min) [r3-verified]
            floatx2 sA0 = { a0.x, a0.y }, sA1 = { a0.z, a0.w };
            floatx2 sA2 = { a1.x, a1.y }, sA3 = { a1.z, a1.w };
            floatx2 oA0 = { b0.x, b0.y }, oA1 = { b0.z, b0.w };
            floatx2 oA2 = { b1.x, b1.y }, oA3 = { b1.z, b1.w };
            floatx2 sC0 = { cc0.x, cc0.y }, sC1 = { cc0.z, cc0.w };
            floatx2 sC2 = { cc1.x, cc1.y }, sC3 = { cc1.z, cc1.w };
            floatx2 oC0 = { d0.x, d0.y }, oC1 = { d0.z, d0.w };
            floatx2 oC2 = { d1.x, d1.y }, oC3 = { d1.z, d1.w };
            float zr[4];
            if (ni == 0) { zr[0] = zp0.x; zr[1] = zp1.x; zr[2] = zp2.x; zr[3] = zp3.x; }
            else         { zr[0] = zp0.y; zr[1] = zp1.y; zr[2] = zp2.y; zr[3] = zp3.y; }
            #pragma unroll
            for (int r = 0; r < 4; r++) {
                float zv = zr[r] + sc.x;
                floatx2 zz = { zv, zv };
                floatx2 tx = PKMAX(PKMAX(PKFMA(zz, sA0, oA0), PKFMA(zz, sA1, oA1)),
                                   PKMAX(PKFMA(zz, sA2, oA2), PKFMA(zz, sA3, oA3)));
                float cvx = fmaxf(tx.x, tx.y);
                floatx2 tn = PKMIN(PKMIN(PKFMA(zz, sC0, oC0), PKFMA(zz, sC1, oC1)),
                                   PKMIN(PKFMA(zz, sC2, oC2), PKFMA(zz, sC3, oC3)));
                float ccv = fminf(tn.x, tn.y);
                float tv = sc.y * cvx + (1.0f - sc.y) * ccv;
                float cpre = accc[mi][ni][r] + sc.z;
                float gpre = accg[mi][ni][r] + sc.w;
                float g = sigm(gpre);
                float cla = gelu_f(cpre);
                obuf[(mb + r) * OSTR + fl] = f2bf(g * tv + (1.0f - g) * cla);
            }
        }
    }
    __syncthreads();   // full 128x128 obuf tile complete
    // cooperative coalesced store: 256B contiguous per row-segment
    #pragma unroll
    for (int e = t; e < 128 * 16; e += 512) {
        int row = e >> 4, c8 = (e & 15) << 3;
        ushort8 v = *(const ushort8*)&obuf[row * OSTR + c8];
        *(ushort8*)&fused[(size_t)(bm * 128 + row) * NF + bf * 128 + c8] = v;
    }
}

// ------------------------------------------------- kernel 5: GEMM2 (fused@Wd + bd) (r0 verbatim)
#define LDS2 64
__global__ __launch_bounds__(512, 4) void gemm2_kernel(
    const unsigned short* __restrict__ A,  // fused [T][1024]
    const unsigned short* __restrict__ Bt, // WdT [256][1024]
    const float* __restrict__ bd, float* __restrict__ out) {
    __shared__ __align__(16) unsigned short As[128 * LDS2];
    __shared__ __align__(16) unsigned short Bs[128 * LDS2];
    const int t = threadIdx.x;
    const int b = blockIdx.x;
    const int xcd = b & 7, j = b >> 3;
    const int bn = j & 1;
    const int bm = (j >> 1) * 8 + xcd;
    const int wave = t >> 6, lane = t & 63;
    const int wm = wave & 1, wn = wave >> 1;
    const int lr = lane & 15, quad = lane >> 4;
    const int srow = wave * 8 + (lane >> 3), scol = (lane & 7) << 3;  // 64 rows/issue
    const unsigned short* gA = A  + (size_t)(bm * 128 + srow) * NF + scol;
    const unsigned short* gB = Bt + (size_t)(bn * 128 + srow) * NF + scol;
    unsigned short* lA = &As[wave * 8 * LDS2];
    unsigned short* lB = &Bs[wave * 8 * LDS2];

    floatx4 acc[4][2];
    #pragma unroll
    for (int i = 0; i < 4; i++)
        #pragma unroll
        for (int jj = 0; jj < 2; jj++) acc[i][jj] = (floatx4)0.0f;

    for (int k0 = 0; k0 < NF; k0 += 64) {
        __syncthreads();
        g2lds16(gA + k0, lA);
        g2lds16(gA + k0 + (size_t)64 * NF, lA + 64 * LDS2);
        g2lds16(gB + k0, lB);
        g2lds16(gB + k0 + (size_t)64 * NF, lB + 64 * LDS2);
        __syncthreads();
        #pragma unroll
        for (int ks = 0; ks < 2; ks++) {
            bf16x8 af[4], bf_[2];
            #pragma unroll
            for (int mi = 0; mi < 4; mi++)
                af[mi] = *(const bf16x8*)&As[(wm * 64 + mi * 16 + lr) * LDS2 + ks * 32 + quad * 8];
            #pragma unroll
            for (int ni = 0; ni < 2; ni++)
                bf_[ni] = *(const bf16x8*)&Bs[(wn * 32 + ni * 16 + lr) * LDS2 + ks * 32 + quad * 8];
            #pragma unroll
            for (int mi = 0; mi < 4; mi++)
                #pragma unroll
                for (int ni = 0; ni < 2; ni++)
                    acc[mi][ni] = __builtin_amdgcn_mfma_f32_16x16x32_bf16(af[mi], bf_[ni], acc[mi][ni], 0, 0, 0);
        }
    }
    #pragma unroll
    for (int mi = 0; mi < 4; mi++)
        #pragma unroll
        for (int ni = 0; ni < 2; ni++) {
            int n = bn * 128 + wn * 32 + ni * 16 + lr;
            float bdv = bd[n];
            #pragma unroll
            for (int r = 0; r < 4; r++) {
                int m = bm * 128 + wm * 64 + mi * 16 + quad * 4 + r;
                out[m * DM + n] = acc[mi][ni][r] + bdv;
            }
        }
}

// ------------------------------------------------------------- launcher (r0 verbatim)
extern "C" void kernel_launch(void* const* d_in, const int* in_sizes, int n_in,
                              void* d_out, int out_size, void* d_ws, size_t ws_size,
                              hipStream_t stream) {
    const float* x     = (const float*)d_in[0];
    const float* Wt    = (const float*)d_in[1];
    const float* bt    = (const float*)d_in[2];
    const float* slx   = (const float*)d_in[3];
    const float* ofx   = (const float*)d_in[4];
    const float* slc   = (const float*)d_in[5];
    const float* ofc   = (const float*)d_in[6];
    const float* alpha = (const float*)d_in[7];
    const float* Wc    = (const float*)d_in[8];
    const float* bc    = (const float*)d_in[9];
    const float* Wg    = (const float*)d_in[10];
    const float* bg    = (const float*)d_in[11];
    const float* Wd    = (const float*)d_in[12];
    const float* bd    = (const float*)d_in[13];
    float* out = (float*)d_out;
    char* ws = (char*)d_ws;

    unsigned int* slot = (unsigned int*)(ws + O_SLOT);
    float* s           = (float*)(ws + O_S);
    unsigned short* Wct = (unsigned short*)(ws + O_WCT);
    unsigned short* Wgt = (unsigned short*)(ws + O_WGT);
    unsigned short* WdT = (unsigned short*)(ws + O_WDT);
    float* WtT          = (float*)(ws + O_WTT);
    unsigned short* xbf = (unsigned short*)(ws + O_XBF);
    int* counts         = (int*)(ws + O_CNT);
    int* cidx           = (int*)(ws + O_CIDX);
    float* cval         = (float*)(ws + O_CVAL);
    unsigned short* fused = (unsigned short*)(ws + O_FUSD);

    pack_kernel<<<1024, 256, 0, stream>>>(Wt, alpha, Wc, Wg, Wd, Wct, Wgt, WdT, WtT, s, slot);
    minmax_kernel<<<128, 256, 0, stream>>>(Wt, slot);
    cand_kernel<<<TTOK, 256, 0, stream>>>(x, slot, xbf, counts, cidx, cval);
    gemm1_kernel<<<2048, 512, 0, stream>>>(
        xbf, Wct, Wgt, bc, bg, counts, cidx, cval, x, WtT, bt,
        slx, ofx, slc, ofc, s, fused);
    gemm2_kernel<<<512, 512, 0, stream>>>(fused, WdT, bd, out);
}

// Round 8
// 289.475 us; speedup vs baseline: 1.1917x; 1.0426x over previous
//
#include <hip/hip_runtime.h>

// ---------------------------------------------------------------- constants
#define TTOK 32768
#define DM   256
#define NF   1024
#define KMAX 32

typedef __attribute__((ext_vector_type(8))) unsigned short ushort8;
typedef __attribute__((ext_vector_type(8))) __bf16 bf16x8;
typedef __attribute__((ext_vector_type(4))) float floatx4;
typedef __attribute__((ext_vector_type(2))) float floatx2;

// packed f32 math (lowers to v_pk_fma_f32 / v_pk_max_f32 / v_pk_min_f32)
#define PKFMA(a,b,c) __builtin_elementwise_fma(a,b,c)
#define PKMAX(a,b)   __builtin_elementwise_max(a,b)
#define PKMIN(a,b)   __builtin_elementwise_min(a,b)

// workspace offsets (all 256B aligned)
constexpr size_t O_SLOT = 0;                                   // 1 uint (max|Wt|)
constexpr size_t O_S    = 256;                                 // 1024 f32 sigmoid(alpha)
constexpr size_t O_WCT  = O_S    + 4096;                       // Wc^T  [1024][256] bf16
constexpr size_t O_WGT  = O_WCT  + (size_t)NF*DM*2;            // Wg^T  [1024][256] bf16
constexpr size_t O_WDT  = O_WGT  + (size_t)NF*DM*2;            // Wd^T  [256][1024] bf16
constexpr size_t O_WTT  = O_WDT  + (size_t)DM*NF*2;            // Wt^T  [256][1024] f32
constexpr size_t O_XBF  = O_WTT  + (size_t)DM*NF*4;            // x bf16 [T][256]
constexpr size_t O_CNT  = O_XBF  + (size_t)TTOK*DM*2;          // counts [T]
constexpr size_t O_CIDX = O_CNT  + (size_t)TTOK*4;             // cand d (raw) [T][KMAX]
constexpr size_t O_CVAL = O_CIDX + (size_t)TTOK*KMAX*4;        // cand val [T][KMAX]
constexpr size_t O_FUSD = O_CVAL + (size_t)TTOK*KMAX*4;        // fused bf16 [T][1024]

__device__ __forceinline__ float bf2f(unsigned short u) {
    union { unsigned int i; float f; } c; c.i = ((unsigned int)u) << 16; return c.f;
}
__device__ __forceinline__ unsigned short f2bf(float v) {
    union { float f; unsigned int i; } c; c.f = v;
    unsigned int b = c.i;
    return (unsigned short)((b + 0x7FFFu + ((b >> 16) & 1u)) >> 16);
}
__device__ __forceinline__ float sigm(float z) { return 1.0f / (1.0f + __expf(-z)); }
// tanh-gelu: max |diff| vs exact erf-gelu ~3e-3, far under 0.266 tolerance
__device__ __forceinline__ float gelu_f(float x) {
    return x * sigm(1.59576912f * (x + 0.044715f * x * x * x));
}
// async global->LDS, 16B per lane; lds dest = wave-uniform base + lane*16 [m97/m104]
__device__ __forceinline__ void g2lds16(const unsigned short* g, unsigned short* l) {
    __builtin_amdgcn_global_load_lds((const __attribute__((address_space(1))) unsigned int*)g,
                                     (__attribute__((address_space(3))) unsigned int*)l, 16, 0, 0);
}

// ------------------------------------------------- kernel 1: pack weights (r0 verbatim)
__global__ void pack_kernel(const float* __restrict__ Wt, const float* __restrict__ alpha,
                            const float* __restrict__ Wc, const float* __restrict__ Wg,
                            const float* __restrict__ Wd,
                            unsigned short* __restrict__ Wct, unsigned short* __restrict__ Wgt,
                            unsigned short* __restrict__ WdT, float* __restrict__ WtT,
                            float* __restrict__ s, unsigned int* __restrict__ slot) {
    int e = blockIdx.x * 256 + threadIdx.x;
    if (e == 0) *slot = 0u;
    { int f = e >> 8, k = e & 255;           // Wc/Wg are [256][1024]
      Wct[e] = f2bf(Wc[k * NF + f]);
      Wgt[e] = f2bf(Wg[k * NF + f]); }
    { int n = e >> 10, k = e & 1023;         // Wd is [1024][256]
      WdT[e] = f2bf(Wd[k * DM + n]); }
    { int d = e >> 10, f = e & 1023;         // Wt is [1024][256]
      WtT[e] = Wt[f * DM + d]; }
    if (e < NF) s[e] = sigm(alpha[e]);
}

// ------------------------------------------------- kernel 2: max|Wt| reduce (r0 verbatim)
__global__ void minmax_kernel(const float* __restrict__ Wt, unsigned int* __restrict__ slot) {
    int g = blockIdx.x * 256 + threadIdx.x;
    float lm = 0.0f;
    for (int i = g; i < NF * DM; i += 128 * 256) lm = fmaxf(lm, fabsf(Wt[i]));
    #pragma unroll
    for (int o = 32; o > 0; o >>= 1) lm = fmaxf(lm, __shfl_xor(lm, o));
    if ((threadIdx.x & 63) == 0) atomicMax(slot, __float_as_uint(lm)); // |w|>=0: uint order ok
}

// ------------------------------------------------- kernel 3: candidates + x->bf16 (r0 verbatim)
__global__ void cand_kernel(const float* __restrict__ x, const unsigned int* __restrict__ slot,
                            unsigned short* __restrict__ xbf, int* __restrict__ counts,
                            int* __restrict__ cidx, float* __restrict__ cval) {
    int i = blockIdx.x, t = threadIdx.x;
    float v = x[i * DM + t];
    xbf[i * DM + t] = f2bf(v);
    float m = v;
    #pragma unroll
    for (int o = 32; o > 0; o >>= 1) m = fmaxf(m, __shfl_xor(m, o));
    __shared__ float wm[4];
    __shared__ int cnt;
    __shared__ int sidx[KMAX];
    __shared__ float sval[KMAX];
    if ((t & 63) == 0) wm[t >> 6] = m;
    if (t == 0) cnt = 0;
    __syncthreads();
    float xmax = fmaxf(fmaxf(wm[0], wm[1]), fmaxf(wm[2], wm[3]));
    float delta = 2.0f * __uint_as_float(*slot);   // >= Wmax - Wmin : exact exclusion bound
    float thr = xmax - delta;
    if (v >= thr) {
        int p = atomicAdd(&cnt, 1);
        if (p < KMAX) { sidx[p] = t; sval[p] = v; }   // raw d index
    }
    __syncthreads();
    int c = cnt;
    if (t == 0) counts[i] = c;
    if (t < (c < KMAX ? c : KMAX)) {
        cidx[i * KMAX + t] = sidx[t];
        cval[i * KMAX + t] = sval[t];
    }
}

// ------------------------------------------------- kernel 4: fused GEMM1
// (x@Wc, x@Wg) MFMA + tropical max-plus + convex/concave + gate blend.
// 128x128 tile, BK=32, 512 thr (8 waves 2Mx4F, wave 64x32 dual-output).
// == r5 VERBATIM (the session's verified-best: gemm1 150us, WRITE=65536) ==
// Final ledger -- every lever tested to a verdict:
//  r7(128x64+reg-diet): spills+L2 thrash. REVERTED.
//  r8(DB 1-barrier loop): null (m97-ceiling behavior). DROPPED.
//  r8(pre-loop prestage): spills. DROPPED.
//  r9(packed pk_fma/pk_max/pk_min epilogue): 190->178. KEPT (r3 text).
//  r10(floatx2-direct par reads): correctness FAIL on HW. REVERTED.
//  r6-phase-split(consume acc early + 2x gather unroll): 206MB scratch --
//    freed AGPRs cannot fund arch-VGPR pressure under launch_bounds(512,4).
//  r7-pair-interleave(WtT float2 gather): clean counters, 150->162. REVERTED.
//    VERDICT: gather is pure-LATENCY-bound (km typically 2-4; serial
//    ~120cy LDS + ~300cy L2 chains). Not transaction-bound, not issue-bound.
// Structural ceiling: 64 arch VGPR + 64 AGPR acc = 128 unified regs/wave
// -> hard 4 waves/SIMD; HBM ~8% and MFMA ~10% both far from roofline; the
// binding constraint is latency-hiding capacity, which no remaining
// register-neutral transform improves.
#define LDSS 32   // ushorts per LDS row, no pad (wave-uniform-base DMA, m104)
#define KPAD 33
#define OSTR 136  // obuf row stride in ushorts (272B, 16q+4r+col bank spread)
__global__ __launch_bounds__(512, 4) void gemm1_kernel(
    const unsigned short* __restrict__ A,   // xbf [T][256]
    const unsigned short* __restrict__ Bct, // [1024][256]
    const unsigned short* __restrict__ Bgt, // [1024][256]
    const float* __restrict__ bc, const float* __restrict__ bg,
    const int* __restrict__ counts, const int* __restrict__ cidx,
    const float* __restrict__ cval, const float* __restrict__ x,
    const float* __restrict__ WtT, const float* __restrict__ bt,
    const float* __restrict__ slx, const float* __restrict__ ofx,
    const float* __restrict__ slc, const float* __restrict__ ofc,
    const float* __restrict__ s, unsigned short* __restrict__ fused) {
    __shared__ __align__(16) char smem[76800];
    unsigned short* As  = (unsigned short*)smem;            // [0, 8K)     K-loop
    unsigned short* Bcs = As + 4096;                        // [8K, 16K)   K-loop
    unsigned short* Bgs = As + 8192;                        // [16K, 24K)  K-loop
    float* par = (float*)smem;                              // [0, 18K)    epilogue (overlay)
    int* sOV  = (int*)(smem + 24576);                       // [24K, 40.5K)
    int* sCnt = (int*)(smem + 41472);                       // 512B
    unsigned short* obuf = (unsigned short*)(smem + 41984); // 34816B
    const int t = threadIdx.x;
    // XCD-aware swizzle (speed heuristic only; correctness order-free)
    const int b = blockIdx.x;
    const int xcd = b & 7, j = b >> 3;
    const int bf = j & 7;
    const int bm = (j >> 3) * 8 + xcd;
    const int wave = t >> 6, lane = t & 63;
    const int wm = wave & 1, wn = wave >> 1;
    const int lr = lane & 15, quad = lane >> 4;
    const int srow = wave * 16 + (lane >> 2), scol = (lane & 3) << 3;
    const unsigned short* gA = A   + (size_t)(bm * 128 + srow) * DM + scol;
    const unsigned short* gC = Bct + (size_t)(bf * 128 + srow) * DM + scol;
    const unsigned short* gG = Bgt + (size_t)(bf * 128 + srow) * DM + scol;
    unsigned short* lA = &As[wave * 16 * LDSS];
    unsigned short* lC = &Bcs[wave * 16 * LDSS];
    unsigned short* lG = &Bgs[wave * 16 * LDSS];

    if (t < 128) sCnt[t] = counts[bm * 128 + t];

    floatx4 accc[4][2], accg[4][2];
    #pragma unroll
    for (int i = 0; i < 4; i++)
        #pragma unroll
        for (int jj = 0; jj < 2; jj++) { accc[i][jj] = (floatx4)0.0f; accg[i][jj] = (floatx4)0.0f; }

    for (int k0 = 0; k0 < DM; k0 += 32) {
        __syncthreads();            // covers sCnt stage (1st iter) + prior ds_reads
        g2lds16(gA + k0, lA);
        g2lds16(gC + k0, lC);
        g2lds16(gG + k0, lG);
        __syncthreads();
        bf16x8 af[4], bcf[2], bgf[2];
        #pragma unroll
        for (int mi = 0; mi < 4; mi++)
            af[mi] = *(const bf16x8*)&As[(wm * 64 + mi * 16 + lr) * LDSS + quad * 8];
        #pragma unroll
        for (int ni = 0; ni < 2; ni++) {
            bcf[ni] = *(const bf16x8*)&Bcs[(wn * 32 + ni * 16 + lr) * LDSS + quad * 8];
            bgf[ni] = *(const bf16x8*)&Bgs[(wn * 32 + ni * 16 + lr) * LDSS + quad * 8];
        }
        #pragma unroll
        for (int mi = 0; mi < 4; mi++)
            #pragma unroll
            for (int ni = 0; ni < 2; ni++) {
                accc[mi][ni] = __builtin_amdgcn_mfma_f32_16x16x32_bf16(af[mi], bcf[ni], accc[mi][ni], 0, 0, 0);
                accg[mi][ni] = __builtin_amdgcn_mfma_f32_16x16x32_bf16(af[mi], bgf[ni], accg[mi][ni], 0, 0, 0);
            }
    }
    __syncthreads();   // staging bufs dead; overlay par

    // ---- stage epilogue params into LDS: par[fl*36 + {0..7 slx, 8..15 ofx,
    //      16..23 slc, 24..31 ofc, 32 bt, 33 s, 34 bc, 35 bg}]
    for (int e = t; e < 1024; e += 512) {
        int ff = e >> 3, w = e & 7;
        int gf = (bf * 128 + ff) * 8 + w;
        par[ff * 36 + w]      = slx[gf];
        par[ff * 36 + 8 + w]  = ofx[gf];
        par[ff * 36 + 16 + w] = slc[gf];
        par[ff * 36 + 24 + w] = ofc[gf];
    }
    if (t < 128) {
        int gf = bf * 128 + t;
        par[t * 36 + 32] = bt[gf];
        par[t * 36 + 33] = s[gf];
        par[t * 36 + 34] = bc[gf];
        par[t * 36 + 35] = bg[gf];
    }
    // ---- stage packed candidate meta (pre-padded: d=0, val=-1e30 -> branchless)
    const int PADV = (int)(((unsigned int)f2bf(-1e30f)) << 16);
    for (int e = t; e < 128 * KMAX; e += 512) {
        int m = e >> 5, k = e & 31;
        int c = sCnt[m];
        int pk = PADV;
        if (k < (c < KMAX ? c : KMAX)) {
            int d  = cidx[(size_t)(bm * 128 + m) * KMAX + k];
            float v = cval[(size_t)(bm * 128 + m) * KMAX + k];
            pk = (int)(((unsigned int)f2bf(v)) << 16) | d;
        }
        sOV[m * KPAD + k] = pk;
    }
    __syncthreads();

    // ---- fused epilogue: tropical z + convex/concave + gate blend ----
    // C/D layout col=lane&15, row=quad*4+r  [verified m89/m91]
    const int f0 = bf * 128 + wn * 32 + lr;    // ni=0 global f; ni=1 is +16
    #pragma unroll
    for (int mi = 0; mi < 4; mi++) {
        const int mb = wm * 64 + mi * 16 + quad * 4;   // local m of r=0
        int c0 = sCnt[mb], c1 = sCnt[mb + 1], c2 = sCnt[mb + 2], c3 = sCnt[mb + 3];
        int k0c = c0 < KMAX ? c0 : KMAX, k1c = c1 < KMAX ? c1 : KMAX;
        int k2c = c2 < KMAX ? c2 : KMAX, k3c = c3 < KMAX ? c3 : KMAX;
        int km = max(max(k0c, k1c), max(k2c, k3c));
        // z packed across the (f0, f0+16) column pair: .x = ni0, .y = ni1  [r3-verified]
        floatx2 zp0 = { -1e30f, -1e30f }, zp1 = zp0, zp2 = zp0, zp3 = zp0;
        for (int k = 0; k < km; k++) {
            int p0 = sOV[(mb + 0) * KPAD + k];
            int p1 = sOV[(mb + 1) * KPAD + k];
            int p2 = sOV[(mb + 2) * KPAD + k];
            int p3 = sOV[(mb + 3) * KPAD + k];
            const float* r0 = WtT + ((p0 & 0xFFFF) << 10) + f0;
            const float* r1 = WtT + ((p1 & 0xFFFF) << 10) + f0;
            const float* r2 = WtT + ((p2 & 0xFFFF) << 10) + f0;
            const float* r3 = WtT + ((p3 & 0xFFFF) << 10) + f0;
            floatx2 w0 = { r0[0], r0[16] };
            floatx2 w1 = { r1[0], r1[16] };
            floatx2 w2 = { r2[0], r2[16] };
            floatx2 w3 = { r3[0], r3[16] };
            float s0 = __int_as_float(p0 & 0xFFFF0000);
            float s1 = __int_as_float(p1 & 0xFFFF0000);
            float s2 = __int_as_float(p2 & 0xFFFF0000);
            float s3 = __int_as_float(p3 & 0xFFFF0000);
            floatx2 v0 = { s0, s0 }, v1 = { s1, s1 }, v2 = { s2, s2 }, v3 = { s3, s3 };
            zp0 = PKMAX(zp0, v0 + w0);
            zp1 = PKMAX(zp1, v1 + w1);
            zp2 = PKMAX(zp2, v2 + w2);
            zp3 = PKMAX(zp3, v3 + w3);
        }
        // exact fallback (count > KMAX, ~never): full 256-d scan
        if (c0 > KMAX || c1 > KMAX || c2 > KMAX || c3 > KMAX) {
            float za[4] = { zp0.x, zp1.x, zp2.x, zp3.x };
            float zb[4] = { zp0.y, zp1.y, zp2.y, zp3.y };
            int cc[4] = { c0, c1, c2, c3 };
            #pragma unroll 1
            for (int r = 0; r < 4; r++) if (cc[r] > KMAX) {
                const float* xr = x + (size_t)(bm * 128 + mb + r) * DM;
                float ma = -1e30f, mbv = -1e30f;
                for (int d = 0; d < DM; d++) {
                    float xv = xr[d];
                    ma  = fmaxf(ma,  xv + WtT[d * NF + f0]);
                    mbv = fmaxf(mbv, xv + WtT[d * NF + f0 + 16]);
                }
                za[r] = ma; zb[r] = mbv;
            }
            zp0.x = za[0]; zp1.x = za[1]; zp2.x = za[2]; zp3.x = za[3];
            zp0.y = zb[0]; zp1.y = zb[1]; zp2.y = zb[2]; zp3.y = zb[3];
        }
        #pragma unroll
        for (int ni = 0; ni < 2; ni++) {
            const int fl = wn * 32 + ni * 16 + lr;
            const float* pp = par + fl * 36;
            float4 a0 = *(const float4*)(pp),      a1 = *(const float4*)(pp + 4);
            float4 b0 = *(const float4*)(pp + 8),  b1 = *(const float4*)(pp + 12);
            float4 cc0 = *(const float4*)(pp + 16), cc1 = *(const float4*)(pp + 20);
            float4 d0 = *(const float4*)(pp + 24), d1 = *(const float4*)(pp + 28);
            float4 sc = *(const float4*)(pp + 32);  // bt, s, bc, bg
            // segment-pair packing for the PWL hulls (v_pk_fma/pk_max/pk_min) [r3-verified]
            floatx2 sA0 = { a0.x, a0.y }, sA1 = { a0.z, a0.w };
            floatx2 sA2 = { a1.x, a1.y }, sA3 = { a1.z, a1.w };
            floatx2 oA0 = { b0.x, b0.y }, oA1 = { b0.z, b0.w };
            floatx2 oA2 = { b1.x, b1.y }, oA3 = { b1.z, b1.w };
            floatx2 sC0 = { cc0.x, cc0.y }, sC1 = { cc0.z, cc0.w };
            floatx2 sC2 = { cc1.x, cc1.y }, sC3 = { cc1.z, cc1.w };
            floatx2 oC0 = { d0.x, d0.y }, oC1 = { d0.z, d0.w };
            floatx2 oC2 = { d1.x, d1.y }, oC3 = { d1.z, d1.w };
            float zr[4];
            if (ni == 0) { zr[0] = zp0.x; zr[1] = zp1.x; zr[2] = zp2.x; zr[3] = zp3.x; }
            else         { zr[0] = zp0.y; zr[1] = zp1.y; zr[2] = zp2.y; zr[3] = zp3.y; }
            #pragma unroll
            for (int r = 0; r < 4; r++) {
                float zv = zr[r] + sc.x;
                floatx2 zz = { zv, zv };
                floatx2 tx = PKMAX(PKMAX(PKFMA(zz, sA0, oA0), PKFMA(zz, sA1, oA1)),
                                   PKMAX(PKFMA(zz, sA2, oA2), PKFMA(zz, sA3, oA3)));
                float cvx = fmaxf(tx.x, tx.y);
                floatx2 tn = PKMIN(PKMIN(PKFMA(zz, sC0, oC0), PKFMA(zz, sC1, oC1)),
                                   PKMIN(PKFMA(zz, sC2, oC2), PKFMA(zz, sC3, oC3)));
                float ccv = fminf(tn.x, tn.y);
                float tv = sc.y * cvx + (1.0f - sc.y) * ccv;
                float cpre = accc[mi][ni][r] + sc.z;
                float gpre = accg[mi][ni][r] + sc.w;
                float g = sigm(gpre);
                float cla = gelu_f(cpre);
                obuf[(mb + r) * OSTR + fl] = f2bf(g * tv + (1.0f - g) * cla);
            }
        }
    }
    __syncthreads();   // full 128x128 obuf tile complete
    // cooperative coalesced store: 256B contiguous per row-segment
    #pragma unroll
    for (int e = t; e < 128 * 16; e += 512) {
        int row = e >> 4, c8 = (e & 15) << 3;
        ushort8 v = *(const ushort8*)&obuf[row * OSTR + c8];
        *(ushort8*)&fused[(size_t)(bm * 128 + row) * NF + bf * 128 + c8] = v;
    }
}

// ------------------------------------------------- kernel 5: GEMM2 (fused@Wd + bd) (r0 verbatim)
#define LDS2 64
__global__ __launch_bounds__(512, 4) void gemm2_kernel(
    const unsigned short* __restrict__ A,  // fused [T][1024]
    const unsigned short* __restrict__ Bt, // WdT [256][1024]
    const float* __restrict__ bd, float* __restrict__ out) {
    __shared__ __align__(16) unsigned short As[128 * LDS2];
    __shared__ __align__(16) unsigned short Bs[128 * LDS2];
    const int t = threadIdx.x;
    const int b = blockIdx.x;
    const int xcd = b & 7, j = b >> 3;
    const int bn = j & 1;
    const int bm = (j >> 1) * 8 + xcd;
    const int wave = t >> 6, lane = t & 63;
    const int wm = wave & 1, wn = wave >> 1;
    const int lr = lane & 15, quad = lane >> 4;
    const int srow = wave * 8 + (lane >> 3), scol = (lane & 7) << 3;  // 64 rows/issue
    const unsigned short* gA = A  + (size_t)(bm * 128 + srow) * NF + scol;
    const unsigned short* gB = Bt + (size_t)(bn * 128 + srow) * NF + scol;
    unsigned short* lA = &As[wave * 8 * LDS2];
    unsigned short* lB = &Bs[wave * 8 * LDS2];

    floatx4 acc[4][2];
    #pragma unroll
    for (int i = 0; i < 4; i++)
        #pragma unroll
        for (int jj = 0; jj < 2; jj++) acc[i][jj] = (floatx4)0.0f;

    for (int k0 = 0; k0 < NF; k0 += 64) {
        __syncthreads();
        g2lds16(gA + k0, lA);
        g2lds16(gA + k0 + (size_t)64 * NF, lA + 64 * LDS2);
        g2lds16(gB + k0, lB);
        g2lds16(gB + k0 + (size_t)64 * NF, lB + 64 * LDS2);
        __syncthreads();
        #pragma unroll
        for (int ks = 0; ks < 2; ks++) {
            bf16x8 af[4], bf_[2];
            #pragma unroll
            for (int mi = 0; mi < 4; mi++)
                af[mi] = *(const bf16x8*)&As[(wm * 64 + mi * 16 + lr) * LDS2 + ks * 32 + quad * 8];
            #pragma unroll
            for (int ni = 0; ni < 2; ni++)
                bf_[ni] = *(const bf16x8*)&Bs[(wn * 32 + ni * 16 + lr) * LDS2 + ks * 32 + quad * 8];
            #pragma unroll
            for (int mi = 0; mi < 4; mi++)
                #pragma unroll
                for (int ni = 0; ni < 2; ni++)
                    acc[mi][ni] = __builtin_amdgcn_mfma_f32_16x16x32_bf16(af[mi], bf_[ni], acc[mi][ni], 0, 0, 0);
        }
    }
    #pragma unroll
    for (int mi = 0; mi < 4; mi++)
        #pragma unroll
        for (int ni = 0; ni < 2; ni++) {
            int n = bn * 128 + wn * 32 + ni * 16 + lr;
            float bdv = bd[n];
            #pragma unroll
            for (int r = 0; r < 4; r++) {
                int m = bm * 128 + wm * 64 + mi * 16 + quad * 4 + r;
                out[m * DM + n] = acc[mi][ni][r] + bdv;
            }
        }
}

// ------------------------------------------------------------- launcher (r0 verbatim)
extern "C" void kernel_launch(void* const* d_in, const int* in_sizes, int n_in,
                              void* d_out, int out_size, void* d_ws, size_t ws_size,
                              hipStream_t stream) {
    const float* x     = (const float*)d_in[0];
    const float* Wt    = (const float*)d_in[1];
    const float* bt    = (const float*)d_in[2];
    const float* slx   = (const float*)d_in[3];
    const float* ofx   = (const float*)d_in[4];
    const float* slc   = (const float*)d_in[5];
    const float* ofc   = (const float*)d_in[6];
    const float* alpha = (const float*)d_in[7];
    const float* Wc    = (const float*)d_in[8];
    const float* bc    = (const float*)d_in[9];
    const float* Wg    = (const float*)d_in[10];
    const float* bg    = (const float*)d_in[11];
    const float* Wd    = (const float*)d_in[12];
    const float* bd    = (const float*)d_in[13];
    float* out = (float*)d_out;
    char* ws = (char*)d_ws;

    unsigned int* slot = (unsigned int*)(ws + O_SLOT);
    float* s           = (float*)(ws + O_S);
    unsigned short* Wct = (unsigned short*)(ws + O_WCT);
    unsigned short* Wgt = (unsigned short*)(ws + O_WGT);
    unsigned short* WdT = (unsigned short*)(ws + O_WDT);
    float* WtT          = (float*)(ws + O_WTT);
    unsigned short* xbf = (unsigned short*)(ws + O_XBF);
    int* counts         = (int*)(ws + O_CNT);
    int* cidx           = (int*)(ws + O_CIDX);
    float* cval         = (float*)(ws + O_CVAL);
    unsigned short* fused = (unsigned short*)(ws + O_FUSD);

    pack_kernel<<<1024, 256, 0, stream>>>(Wt, alpha, Wc, Wg, Wd, Wct, Wgt, WdT, WtT, s, slot);
    minmax_kernel<<<128, 256, 0, stream>>>(Wt, slot);
    cand_kernel<<<TTOK, 256, 0, stream>>>(x, slot, xbf, counts, cidx, cval);
    gemm1_kernel<<<2048, 512, 0, stream>>>(
        xbf, Wct, Wgt, bc, bg, counts, cidx, cval, x, WtT, bt,
        slx, ofx, slc, ofc, s, fused);
    gemm2_kernel<<<512, 512, 0, stream>>>(fused, WdT, bd, out);
}